// Round 1
// baseline (1347.461 us; speedup 1.0000x reference)
//
#include <hip/hip_runtime.h>
#include <stdint.h>

typedef unsigned short u16;
typedef __bf16 bf16x8 __attribute__((ext_vector_type(8)));
typedef float f32x4 __attribute__((ext_vector_type(4)));
typedef unsigned short u16x8 __attribute__((ext_vector_type(8)));

#define MFMA16(a, b, c) __builtin_amdgcn_mfma_f32_16x16x32_bf16((a), (b), (c), 0, 0, 0)

// B=4, N=8192, DIM=1024, H=16, DH=64, W=128 -> NW=64 windows, INNER=1024
#define SEQ_N 8192
#define NWIN 64

__device__ __forceinline__ u16 f2bf(float f) {
  union { float f; uint32_t u; } v; v.f = f;
  return (u16)((v.u + 0x7fffu + ((v.u >> 16) & 1u)) >> 16);  // RNE
}

__device__ __forceinline__ void load_lds16(const u16* g, u16* l) {
  // async global->LDS, 16B/lane; LDS dest = wave-uniform base + lane*16
  __builtin_amdgcn_global_load_lds((const __attribute__((address_space(1))) void*)g,
                                   (__attribute__((address_space(3))) void*)l, 16, 0, 0);
}

// ---------------- cast fp32 -> bf16, 8 elems/thread ----------------
__global__ __launch_bounds__(256) void cast_bf16_kernel(const float* __restrict__ src,
                                                        u16* __restrict__ dst, int n8) {
  int i = blockIdx.x * 256 + threadIdx.x;
  if (i >= n8) return;
  const float4* s = (const float4*)src + (size_t)i * 2;
  float4 a = s[0], b = s[1];
  u16x8 o;
  o[0] = f2bf(a.x); o[1] = f2bf(a.y); o[2] = f2bf(a.z); o[3] = f2bf(a.w);
  o[4] = f2bf(b.x); o[5] = f2bf(b.y); o[6] = f2bf(b.z); o[7] = f2bf(b.w);
  *((u16x8*)dst + i) = o;
}

// ------------- transpose + cast: dst[n][k] = src[k][n] (bf16) -------------
// n < 1024 reads srcA (row width 1024); n >= 1024 reads srcB (row width bcols).
__global__ __launch_bounds__(256) void transpose_cast_kernel(u16* __restrict__ dst,
                                                             const float* __restrict__ srcA,
                                                             const float* __restrict__ srcB,
                                                             int bcols) {
  __shared__ float tile[32][33];
  const int tx = threadIdx.x & 31, ty = threadIdx.x >> 5;  // ty 0..7
  const int n0 = blockIdx.x * 32, k0 = blockIdx.y * 32;
#pragma unroll
  for (int i = 0; i < 4; ++i) {
    int k = k0 + ty + i * 8;
    int n = n0 + tx;
    float v = (n < 1024) ? srcA[(size_t)k * 1024 + n]
                         : srcB[(size_t)k * bcols + (n - 1024)];
    tile[ty + i * 8][tx] = v;
  }
  __syncthreads();
#pragma unroll
  for (int i = 0; i < 4; ++i) {
    int n = n0 + ty + i * 8;
    int k = k0 + tx;
    dst[(size_t)n * 1024 + k] = f2bf(tile[tx][ty + i * 8]);
  }
}

// ---------------- GEMM: C[M][N] = A[M][1024] @ Bt[N][1024]^T ----------------
// m97 structure: 128x128 tile, BK=32, 4 waves each 64x64 (4x4 of 16x16x32 MFMA),
// global_load_lds width-16 staging. MODE 0: split bf16 epilogue to q/k/v buffers.
// MODE 1: fp32 out + bias.
template <int MODE>
__global__ __launch_bounds__(256, 2) void gemm_bt_kernel(
    const u16* __restrict__ A, const u16* __restrict__ Bt,
    u16* __restrict__ qo, u16* __restrict__ ko, u16* __restrict__ vo,
    float* __restrict__ out, const float* __restrict__ bias) {
  constexpr int K = 1024;
  __shared__ u16 As[128 * 32];
  __shared__ u16 Bs[128 * 32];
  const int tid = threadIdx.x;
  const int wave = tid >> 6, lane = tid & 63;
  const int quad = lane >> 4, l15 = lane & 15;
  const int bm = blockIdx.y, bn = blockIdx.x;
  const int wm = wave >> 1, wn = wave & 1;

  f32x4 acc[4][4] = {};

  // staging: wave w loads rows [w*32, w*32+32) of each tile, two 16-row chunks
  const size_t aoff0 = (size_t)(bm * 128 + wave * 32 + (lane >> 2)) * K + (lane & 3) * 8;
  const size_t boff0 = (size_t)(bn * 128 + wave * 32 + (lane >> 2)) * K + (lane & 3) * 8;
  u16* as0 = &As[wave * 1024];
  u16* bs0 = &Bs[wave * 1024];

  for (int kt = 0; kt < K / 32; ++kt) {
    __syncthreads();
    const u16* ga = A + aoff0 + kt * 32;
    const u16* gb = Bt + boff0 + kt * 32;
    load_lds16(ga, as0);
    load_lds16(ga + 16 * K, as0 + 512);
    load_lds16(gb, bs0);
    load_lds16(gb + 16 * K, bs0 + 512);
    __syncthreads();

    bf16x8 af[4], bf[4];
#pragma unroll
    for (int mt = 0; mt < 4; ++mt)
      af[mt] = *(const bf16x8*)&As[(wm * 64 + mt * 16 + l15) * 32 + quad * 8];
#pragma unroll
    for (int nt = 0; nt < 4; ++nt)
      bf[nt] = *(const bf16x8*)&Bs[(wn * 64 + nt * 16 + l15) * 32 + quad * 8];
#pragma unroll
    for (int mt = 0; mt < 4; ++mt)
#pragma unroll
      for (int nt = 0; nt < 4; ++nt)
        acc[mt][nt] = MFMA16(af[mt], bf[nt], acc[mt][nt]);
  }

  const int row0 = bm * 128 + wm * 64;
  const int col0 = bn * 128 + wn * 64;
#pragma unroll
  for (int mt = 0; mt < 4; ++mt) {
#pragma unroll
    for (int nt = 0; nt < 4; ++nt) {
      const int col = col0 + nt * 16 + l15;
      if (MODE == 0) {
        u16* dst = (col < 1024) ? qo : ((col < 2048) ? ko : vo);
        const int cc = col & 1023;
#pragma unroll
        for (int r = 0; r < 4; ++r) {
          const int row = row0 + mt * 16 + quad * 4 + r;
          dst[(size_t)row * 1024 + cc] = f2bf(acc[mt][nt][r]);
        }
      } else {
        const float bv = bias[col];
#pragma unroll
        for (int r = 0; r < 4; ++r) {
          const int row = row0 + mt * 16 + quad * 4 + r;
          out[(size_t)row * 1024 + col] = acc[mt][nt][r] + bv;
        }
      }
    }
  }
}

// ---------------- windowed attention ----------------
// One block per (b, h, window): Q 128x64, K/V 256x64 (prev+cur window; window 0's
// prev is zeros -> sim=0, INCLUDED in softmax, matching the reference pad).
// Wave w owns query rows [w*32, w*32+32). Q/K frags direct from global; V staged
// transposed in LDS; P goes through a per-wave LDS bounce (C-layout -> A-layout).
__global__ __launch_bounds__(256, 2) void attn_kernel(const u16* __restrict__ qb,
                                                      const u16* __restrict__ kb,
                                                      const u16* __restrict__ vb,
                                                      u16* __restrict__ ob) {
  __shared__ u16 Vt[64][264];      // [d][token], +8 pad
  __shared__ u16 Ps[4 * 2048];     // per-wave double-buffered 32x32 P chunk
  const int tid = threadIdx.x;
  const int wave = tid >> 6, lane = tid & 63;
  const int quad = lane >> 4, l15 = lane & 15;
  const int blk = blockIdx.x;
  const int wi = blk & (NWIN - 1);
  const int bh = blk >> 6;                       // b*16 + h
  const long tok0 = (long)(bh >> 4) * SEQ_N + (long)wi * 128;  // first query token
  const int hoff = (bh & 15) * 64;
  const long qbase = tok0 * 1024 + hoff;
  const long kbase = (tok0 - 128) * 1024 + hoff; // key token j at kbase + j*1024

  // ---- stage V transposed: thread t handles key token t ----
  {
    const int t = tid;
    const bool pad = (wi == 0) && (t < 128);
#pragma unroll
    for (int d0 = 0; d0 < 64; d0 += 8) {
      u16x8 v8;
      if (pad) {
        v8 = (u16x8)0;
      } else {
        v8 = *(const u16x8*)(vb + (kbase + (long)t * 1024 + d0));
      }
#pragma unroll
      for (int j = 0; j < 8; ++j) Vt[d0 + j][t] = v8[j];
    }
  }

  // ---- Q fragments (A-operand, direct from global) ----
  bf16x8 qf[2][2];
#pragma unroll
  for (int mt = 0; mt < 2; ++mt)
#pragma unroll
    for (int kk = 0; kk < 2; ++kk)
      qf[mt][kk] = *(const bf16x8*)(qb + (qbase + (long)(wave * 32 + mt * 16 + l15) * 1024 +
                                          kk * 32 + quad * 8));

  // ---- S = Q K^T (2 m-tiles x 16 n-tiles, fp32 acc in regs) ----
  f32x4 s[2][16] = {};
#pragma unroll 4
  for (int nt = 0; nt < 16; ++nt) {
    if (!((wi == 0) && (nt < 8))) {  // zero-pad keys -> s stays 0
      const long kt = kbase + (long)(nt * 16 + l15) * 1024;
      bf16x8 kf0 = *(const bf16x8*)(kb + (kt + quad * 8));
      bf16x8 kf1 = *(const bf16x8*)(kb + (kt + 32 + quad * 8));
#pragma unroll
      for (int mt = 0; mt < 2; ++mt) {
        s[mt][nt] = MFMA16(qf[mt][0], kf0, s[mt][nt]);
        s[mt][nt] = MFMA16(qf[mt][1], kf1, s[mt][nt]);
      }
    }
  }

  // ---- masked softmax over 256 keys (16-lane shuffle reductions) ----
#pragma unroll
  for (int mt = 0; mt < 2; ++mt) {
#pragma unroll
    for (int r = 0; r < 4; ++r) {
      const int row = wave * 32 + mt * 16 + quad * 4 + r;
      float m = -3.0e38f;
      float vals[16];
#pragma unroll
      for (int nt = 0; nt < 16; ++nt) {
        const int col = nt * 16 + l15;
        float x = s[mt][nt][r] * 0.125f;   // dh^-0.5
        if (col > row + 128) x = -3.0e38f; // causal: key j visible iff j <= i+128
        vals[nt] = x;
        m = fmaxf(m, x);
      }
      m = fmaxf(m, __shfl_xor(m, 1));
      m = fmaxf(m, __shfl_xor(m, 2));
      m = fmaxf(m, __shfl_xor(m, 4));
      m = fmaxf(m, __shfl_xor(m, 8));
      float sum = 0.f;
#pragma unroll
      for (int nt = 0; nt < 16; ++nt) {
        float e = __expf(vals[nt] - m);
        vals[nt] = e;
        sum += e;
      }
      sum += __shfl_xor(sum, 1);
      sum += __shfl_xor(sum, 2);
      sum += __shfl_xor(sum, 4);
      sum += __shfl_xor(sum, 8);
      const float inv = 1.0f / sum;
#pragma unroll
      for (int nt = 0; nt < 16; ++nt) s[mt][nt][r] = vals[nt] * inv;
    }
  }

  __syncthreads();  // Vt ready for all waves

  // ---- O = P V : per 32-key chunk, bounce P through LDS into A-layout ----
  f32x4 o[2][4] = {};
  for (int ks = 0; ks < 8; ++ks) {
    u16* myP = &Ps[wave * 2048 + (ks & 1) * 1024];  // 32 rows x 32 cols bf16
#pragma unroll
    for (int mt = 0; mt < 2; ++mt)
#pragma unroll
      for (int half = 0; half < 2; ++half) {
        const int nt = ks * 2 + half;
#pragma unroll
        for (int r = 0; r < 4; ++r)
          myP[(mt * 16 + quad * 4 + r) * 32 + half * 16 + l15] = f2bf(s[mt][nt][r]);
      }
    bf16x8 pf[2];
    pf[0] = *(const bf16x8*)&myP[l15 * 32 + quad * 8];
    pf[1] = *(const bf16x8*)&myP[(16 + l15) * 32 + quad * 8];
#pragma unroll
    for (int ont = 0; ont < 4; ++ont) {
      bf16x8 vf = *(const bf16x8*)&Vt[ont * 16 + l15][ks * 32 + quad * 8];
      o[0][ont] = MFMA16(pf[0], vf, o[0][ont]);
      o[1][ont] = MFMA16(pf[1], vf, o[1][ont]);
    }
  }

  // ---- write O (bf16, token-major [B*N][1024]) ----
#pragma unroll
  for (int mt = 0; mt < 2; ++mt)
#pragma unroll
    for (int ont = 0; ont < 4; ++ont)
#pragma unroll
      for (int r = 0; r < 4; ++r) {
        const int row = wave * 32 + mt * 16 + quad * 4 + r;
        const int col = ont * 16 + l15;
        ob[qbase + (long)row * 1024 + col] = f2bf(o[mt][ont][r]);
      }
}

extern "C" void kernel_launch(void* const* d_in, const int* in_sizes, int n_in,
                              void* d_out, int out_size, void* d_ws, size_t ws_size,
                              hipStream_t stream) {
  const float* x   = (const float*)d_in[0];
  const float* wq  = (const float*)d_in[1];
  const float* wkv = (const float*)d_in[2];
  const float* wo  = (const float*)d_in[3];
  const float* bo  = (const float*)d_in[4];
  float* out = (float*)d_out;

  const size_t XE = (size_t)4 * SEQ_N * 1024;  // 33,554,432 tokens*dim elements
  u16* ws = (u16*)d_ws;
  u16* xb    = ws;            // bf16 x            (reused as attention output buffer)
  u16* qbuf  = ws + XE;
  u16* kbuf  = ws + 2 * XE;
  u16* vbuf  = ws + 3 * XE;
  u16* wqkvT = ws + 4 * XE;           // [3072][1024]
  u16* woT   = wqkvT + 3072 * 1024;   // [1024][1024]
  u16* obuf  = xb;                    // xb dead after QKV GEMM

  cast_bf16_kernel<<<16384, 256, 0, stream>>>(x, xb, (int)(XE / 8));
  transpose_cast_kernel<<<dim3(96, 32), 256, 0, stream>>>(wqkvT, wq, wkv, 2048);
  transpose_cast_kernel<<<dim3(32, 32), 256, 0, stream>>>(woT, wo, wo, 1024);
  gemm_bt_kernel<0><<<dim3(24, 256), 256, 0, stream>>>(xb, wqkvT, qbuf, kbuf, vbuf,
                                                       nullptr, nullptr);
  attn_kernel<<<4096, 256, 0, stream>>>(qbuf, kbuf, vbuf, obuf);
  gemm_bt_kernel<1><<<dim3(8, 256), 256, 0, stream>>>(obuf, woT, nullptr, nullptr, nullptr,
                                                      out, bo);
}

// Round 2
// 710.338 us; speedup vs baseline: 1.8969x; 1.8969x over previous
//
#include <hip/hip_runtime.h>
#include <stdint.h>

typedef unsigned short u16;
typedef __bf16 bf16x8 __attribute__((ext_vector_type(8)));
typedef float f32x4 __attribute__((ext_vector_type(4)));
typedef unsigned short u16x8 __attribute__((ext_vector_type(8)));

#define MFMA16(a, b, c) __builtin_amdgcn_mfma_f32_16x16x32_bf16((a), (b), (c), 0, 0, 0)

// B=4, N=8192, DIM=1024, H=16, DH=64, W=128 -> NW=64 windows, INNER=1024
#define SEQ_N 8192
#define NWIN 64

__device__ __forceinline__ u16 f2bf(float f) {
  union { float f; uint32_t u; } v; v.f = f;
  return (u16)((v.u + 0x7fffu + ((v.u >> 16) & 1u)) >> 16);  // RNE
}

__device__ __forceinline__ void load_lds16(const u16* g, u16* l) {
  // async global->LDS, 16B/lane; LDS dest = wave-uniform base + lane*16
  __builtin_amdgcn_global_load_lds((const __attribute__((address_space(1))) void*)g,
                                   (__attribute__((address_space(3))) void*)l, 16, 0, 0);
}

// ---------------- cast fp32 -> bf16, 8 elems/thread ----------------
__global__ __launch_bounds__(256) void cast_bf16_kernel(const float* __restrict__ src,
                                                        u16* __restrict__ dst, int n8) {
  int i = blockIdx.x * 256 + threadIdx.x;
  if (i >= n8) return;
  const float4* s = (const float4*)src + (size_t)i * 2;
  float4 a = s[0], b = s[1];
  u16x8 o;
  o[0] = f2bf(a.x); o[1] = f2bf(a.y); o[2] = f2bf(a.z); o[3] = f2bf(a.w);
  o[4] = f2bf(b.x); o[5] = f2bf(b.y); o[6] = f2bf(b.z); o[7] = f2bf(b.w);
  *((u16x8*)dst + i) = o;
}

// ------------- transpose + cast: dst[n][k] = src[k][n] (bf16) -------------
// n < 1024 reads srcA (row width 1024); n >= 1024 reads srcB (row width bcols).
__global__ __launch_bounds__(256) void transpose_cast_kernel(u16* __restrict__ dst,
                                                             const float* __restrict__ srcA,
                                                             const float* __restrict__ srcB,
                                                             int bcols) {
  __shared__ float tile[32][33];
  const int tx = threadIdx.x & 31, ty = threadIdx.x >> 5;  // ty 0..7
  const int n0 = blockIdx.x * 32, k0 = blockIdx.y * 32;
#pragma unroll
  for (int i = 0; i < 4; ++i) {
    int k = k0 + ty + i * 8;
    int n = n0 + tx;
    float v = (n < 1024) ? srcA[(size_t)k * 1024 + n]
                         : srcB[(size_t)k * bcols + (n - 1024)];
    tile[ty + i * 8][tx] = v;
  }
  __syncthreads();
#pragma unroll
  for (int i = 0; i < 4; ++i) {
    int n = n0 + ty + i * 8;
    int k = k0 + tx;
    dst[(size_t)n * 1024 + k] = f2bf(tile[tx][ty + i * 8]);
  }
}

// ---------------- GEMM: C[M][N] = A[M][1024] @ Bt[N][1024]^T ----------------
// m97 structure: 128x128 tile, BK=32, 4 waves each 64x64 (4x4 of 16x16x32 MFMA),
// global_load_lds width-16 staging. MODE 0: split bf16 epilogue to q/k/v buffers.
// MODE 1: fp32 out + bias.
template <int MODE>
__global__ __launch_bounds__(256, 2) void gemm_bt_kernel(
    const u16* __restrict__ A, const u16* __restrict__ Bt,
    u16* __restrict__ qo, u16* __restrict__ ko, u16* __restrict__ vo,
    float* __restrict__ out, const float* __restrict__ bias) {
  constexpr int K = 1024;
  __shared__ u16 As[128 * 32];
  __shared__ u16 Bs[128 * 32];
  const int tid = threadIdx.x;
  const int wave = tid >> 6, lane = tid & 63;
  const int quad = lane >> 4, l15 = lane & 15;
  const int bm = blockIdx.y, bn = blockIdx.x;
  const int wm = wave >> 1, wn = wave & 1;

  f32x4 acc[4][4] = {};

  // staging: wave w loads rows [w*32, w*32+32) of each tile, two 16-row chunks
  const size_t aoff0 = (size_t)(bm * 128 + wave * 32 + (lane >> 2)) * K + (lane & 3) * 8;
  const size_t boff0 = (size_t)(bn * 128 + wave * 32 + (lane >> 2)) * K + (lane & 3) * 8;
  u16* as0 = &As[wave * 1024];
  u16* bs0 = &Bs[wave * 1024];

  for (int kt = 0; kt < K / 32; ++kt) {
    __syncthreads();
    const u16* ga = A + aoff0 + kt * 32;
    const u16* gb = Bt + boff0 + kt * 32;
    load_lds16(ga, as0);
    load_lds16(ga + 16 * K, as0 + 512);
    load_lds16(gb, bs0);
    load_lds16(gb + 16 * K, bs0 + 512);
    __syncthreads();

    bf16x8 af[4], bf[4];
#pragma unroll
    for (int mt = 0; mt < 4; ++mt)
      af[mt] = *(const bf16x8*)&As[(wm * 64 + mt * 16 + l15) * 32 + quad * 8];
#pragma unroll
    for (int nt = 0; nt < 4; ++nt)
      bf[nt] = *(const bf16x8*)&Bs[(wn * 64 + nt * 16 + l15) * 32 + quad * 8];
#pragma unroll
    for (int mt = 0; mt < 4; ++mt)
#pragma unroll
      for (int nt = 0; nt < 4; ++nt)
        acc[mt][nt] = MFMA16(af[mt], bf[nt], acc[mt][nt]);
  }

  const int row0 = bm * 128 + wm * 64;
  const int col0 = bn * 128 + wn * 64;
#pragma unroll
  for (int mt = 0; mt < 4; ++mt) {
#pragma unroll
    for (int nt = 0; nt < 4; ++nt) {
      const int col = col0 + nt * 16 + l15;
      if (MODE == 0) {
        u16* dst = (col < 1024) ? qo : ((col < 2048) ? ko : vo);
        const int cc = col & 1023;
#pragma unroll
        for (int r = 0; r < 4; ++r) {
          const int row = row0 + mt * 16 + quad * 4 + r;
          dst[(size_t)row * 1024 + cc] = f2bf(acc[mt][nt][r]);
        }
      } else {
        const float bv = bias[col];
#pragma unroll
        for (int r = 0; r < 4; ++r) {
          const int row = row0 + mt * 16 + quad * 4 + r;
          out[(size_t)row * 1024 + col] = acc[mt][nt][r] + bv;
        }
      }
    }
  }
}

// ---------------- windowed attention ----------------
// One block per (b, h, window): Q 128x64, K/V 256x64 (prev+cur window; window 0's
// prev is zeros -> sim=0, INCLUDED in softmax, matching the reference pad).
// Wave w owns query rows [w*32, w*32+32). Q/K frags direct from global; V staged
// transposed in LDS; P goes through a per-wave LDS bounce (C-layout -> A-layout).
// CRITICAL: all loops touching s[][] are fully unrolled (compile-time indices);
// round-1 version had a runtime-indexed PV loop -> s[] spilled to scratch ->
// 2.9 GB of HBM traffic and 787 us.
__global__ __launch_bounds__(256, 2) void attn_kernel(const u16* __restrict__ qb,
                                                      const u16* __restrict__ kb,
                                                      const u16* __restrict__ vb,
                                                      u16* __restrict__ ob) {
  __shared__ u16 Vt[64][264];      // [d][token], +8 pad
  __shared__ u16 Ps[4 * 2048];     // per-wave double-buffered 32x32 P chunk
  const int tid = threadIdx.x;
  const int wave = tid >> 6, lane = tid & 63;
  const int quad = lane >> 4, l15 = lane & 15;
  const int blk = blockIdx.x;
  const int wi = blk & (NWIN - 1);
  const int bh = blk >> 6;                       // b*16 + h
  const long tok0 = (long)(bh >> 4) * SEQ_N + (long)wi * 128;  // first query token
  const int hoff = (bh & 15) * 64;
  const long qbase = tok0 * 1024 + hoff;
  const long kbase = (tok0 - 128) * 1024 + hoff; // key token j at kbase + j*1024

  // ---- stage V transposed: thread t handles key token t ----
  {
    const int t = tid;
    const bool pad = (wi == 0) && (t < 128);
#pragma unroll
    for (int d0 = 0; d0 < 64; d0 += 8) {
      u16x8 v8;
      if (pad) {
        v8 = (u16x8)0;
      } else {
        v8 = *(const u16x8*)(vb + (kbase + (long)t * 1024 + d0));
      }
#pragma unroll
      for (int j = 0; j < 8; ++j) Vt[d0 + j][t] = v8[j];
    }
  }

  // ---- Q fragments (A-operand, direct from global) ----
  bf16x8 qf[2][2];
#pragma unroll
  for (int mt = 0; mt < 2; ++mt)
#pragma unroll
    for (int kk = 0; kk < 2; ++kk)
      qf[mt][kk] = *(const bf16x8*)(qb + (qbase + (long)(wave * 32 + mt * 16 + l15) * 1024 +
                                          kk * 32 + quad * 8));

  // ---- S = Q K^T (2 m-tiles x 16 n-tiles, fp32 acc in regs) ----
  f32x4 s[2][16] = {};
#pragma unroll
  for (int nt = 0; nt < 16; ++nt) {
    if (!((wi == 0) && (nt < 8))) {  // zero-pad keys -> s stays 0
      const long kt = kbase + (long)(nt * 16 + l15) * 1024;
      bf16x8 kf0 = *(const bf16x8*)(kb + (kt + quad * 8));
      bf16x8 kf1 = *(const bf16x8*)(kb + (kt + 32 + quad * 8));
#pragma unroll
      for (int mt = 0; mt < 2; ++mt) {
        s[mt][nt] = MFMA16(qf[mt][0], kf0, s[mt][nt]);
        s[mt][nt] = MFMA16(qf[mt][1], kf1, s[mt][nt]);
      }
    }
  }

  // ---- masked softmax over 256 keys, fully in place on s (no temp array) ----
#pragma unroll
  for (int mt = 0; mt < 2; ++mt) {
#pragma unroll
    for (int r = 0; r < 4; ++r) {
      const int row = wave * 32 + mt * 16 + quad * 4 + r;
      float m = -3.0e38f;
#pragma unroll
      for (int nt = 0; nt < 16; ++nt) {
        const int col = nt * 16 + l15;
        float x = s[mt][nt][r] * 0.125f;   // dh^-0.5
        if (col > row + 128) x = -3.0e38f; // causal: key j visible iff j <= i+128
        s[mt][nt][r] = x;
        m = fmaxf(m, x);
      }
      m = fmaxf(m, __shfl_xor(m, 1));
      m = fmaxf(m, __shfl_xor(m, 2));
      m = fmaxf(m, __shfl_xor(m, 4));
      m = fmaxf(m, __shfl_xor(m, 8));
      float sum = 0.f;
#pragma unroll
      for (int nt = 0; nt < 16; ++nt) {
        float e = __expf(s[mt][nt][r] - m);
        s[mt][nt][r] = e;
        sum += e;
      }
      sum += __shfl_xor(sum, 1);
      sum += __shfl_xor(sum, 2);
      sum += __shfl_xor(sum, 4);
      sum += __shfl_xor(sum, 8);
      const float inv = 1.0f / sum;
#pragma unroll
      for (int nt = 0; nt < 16; ++nt) s[mt][nt][r] *= inv;
    }
  }

  __syncthreads();  // Vt ready for all waves

  // ---- O = P V : per 32-key chunk, bounce P through LDS into A-layout ----
  // Fully unrolled: every s[][] index is a compile-time constant.
  f32x4 o[2][4] = {};
#pragma unroll
  for (int ks = 0; ks < 8; ++ks) {
    u16* myP = &Ps[wave * 2048 + (ks & 1) * 1024];  // 32 rows x 32 cols bf16
#pragma unroll
    for (int mt = 0; mt < 2; ++mt)
#pragma unroll
      for (int half = 0; half < 2; ++half) {
        const int nt = ks * 2 + half;
#pragma unroll
        for (int r = 0; r < 4; ++r)
          myP[(mt * 16 + quad * 4 + r) * 32 + half * 16 + l15] = f2bf(s[mt][nt][r]);
      }
    bf16x8 pf[2];
    pf[0] = *(const bf16x8*)&myP[l15 * 32 + quad * 8];
    pf[1] = *(const bf16x8*)&myP[(16 + l15) * 32 + quad * 8];
#pragma unroll
    for (int ont = 0; ont < 4; ++ont) {
      bf16x8 vf = *(const bf16x8*)&Vt[ont * 16 + l15][ks * 32 + quad * 8];
      o[0][ont] = MFMA16(pf[0], vf, o[0][ont]);
      o[1][ont] = MFMA16(pf[1], vf, o[1][ont]);
    }
  }

  // ---- write O (bf16, token-major [B*N][1024]) ----
#pragma unroll
  for (int mt = 0; mt < 2; ++mt)
#pragma unroll
    for (int ont = 0; ont < 4; ++ont)
#pragma unroll
      for (int r = 0; r < 4; ++r) {
        const int row = wave * 32 + mt * 16 + quad * 4 + r;
        const int col = ont * 16 + l15;
        ob[qbase + (long)row * 1024 + col] = f2bf(o[mt][ont][r]);
      }
}

extern "C" void kernel_launch(void* const* d_in, const int* in_sizes, int n_in,
                              void* d_out, int out_size, void* d_ws, size_t ws_size,
                              hipStream_t stream) {
  const float* x   = (const float*)d_in[0];
  const float* wq  = (const float*)d_in[1];
  const float* wkv = (const float*)d_in[2];
  const float* wo  = (const float*)d_in[3];
  const float* bo  = (const float*)d_in[4];
  float* out = (float*)d_out;

  const size_t XE = (size_t)4 * SEQ_N * 1024;  // 33,554,432 tokens*dim elements
  u16* ws = (u16*)d_ws;
  u16* xb    = ws;            // bf16 x            (reused as attention output buffer)
  u16* qbuf  = ws + XE;
  u16* kbuf  = ws + 2 * XE;
  u16* vbuf  = ws + 3 * XE;
  u16* wqkvT = ws + 4 * XE;           // [3072][1024]
  u16* woT   = wqkvT + 3072 * 1024;   // [1024][1024]
  u16* obuf  = xb;                    // xb dead after QKV GEMM

  cast_bf16_kernel<<<16384, 256, 0, stream>>>(x, xb, (int)(XE / 8));
  transpose_cast_kernel<<<dim3(96, 32), 256, 0, stream>>>(wqkvT, wq, wkv, 2048);
  transpose_cast_kernel<<<dim3(32, 32), 256, 0, stream>>>(woT, wo, wo, 1024);
  gemm_bt_kernel<0><<<dim3(24, 256), 256, 0, stream>>>(xb, wqkvT, qbuf, kbuf, vbuf,
                                                       nullptr, nullptr);
  attn_kernel<<<4096, 256, 0, stream>>>(qbuf, kbuf, vbuf, obuf);
  gemm_bt_kernel<1><<<dim3(8, 256), 256, 0, stream>>>(obuf, woT, nullptr, nullptr, nullptr,
                                                      out, bo);
}